// Round 9
// baseline (272.759 us; speedup 1.0000x reference)
//
#include <hip/hip_runtime.h>
#include <math.h>

#define Hn 1024
#define Dn 256
#define Bn 8
#define DTf 0.125f

typedef __attribute__((ext_vector_type(4))) float f32x4;

constexpr float kA[6][5] = {
  {0.f, 0.f, 0.f, 0.f, 0.f},
  {1.0f/5.0f, 0.f, 0.f, 0.f, 0.f},
  {3.0f/40.0f, 9.0f/40.0f, 0.f, 0.f, 0.f},
  {44.0f/45.0f, -56.0f/15.0f, 32.0f/9.0f, 0.f, 0.f},
  {19372.0f/6561.0f, -25360.0f/2187.0f, 64448.0f/6561.0f, -212.0f/729.0f, 0.f},
  {9017.0f/3168.0f, -355.0f/33.0f, 46732.0f/5247.0f, 49.0f/176.0f, -5103.0f/18656.0f}
};
constexpr float kC[6] = {0.f, 0.2f, 0.3f, 0.8f, 8.0f/9.0f, 1.0f};
constexpr float kBW[6] = {35.0f/384.0f, 0.f, 500.0f/1113.0f, 125.0f/192.0f,
                          -2187.0f/6784.0f, 11.0f/84.0f};

__device__ __forceinline__ float fast_tanh(float x) {
  const float ax = fabsf(x);
  const float z = __expf(-2.0f * ax);
  const float t = (1.0f - z) * __builtin_amdgcn_rcpf(1.0f + z);
  return copysignf(t, x);
}

// ---------------- precompute ----------------
// wg 0..255: M = (W1^T W1).*(W2 W2^T); 256..511: Z = W2@W1;
// 512: scal/flags; 513..560: hbuf = 2.0f sentinel
__global__ __launch_bounds__(256) void precomp(
    const float* __restrict__ W1, const float* __restrict__ W2,
    float* __restrict__ Mm, float* __restrict__ Zz,
    float* __restrict__ hbuf, float* __restrict__ scal,
    unsigned* __restrict__ flags) {
  __shared__ float sm[8704];
  const int tid = threadIdx.x;
  const int wg = blockIdx.x;
  if (wg < 256) {
    float* a1k  = sm;            // [32][64]
    float* a1l  = sm + 2048;     // [32][64]
    float* w2kT = sm + 4096;     // [32][72]
    float* w2lT = sm + 6400;     // [32][72]
    const int k0 = (wg & 15) * 64, l0 = (wg >> 4) * 64;
    const int kq = tid & 15, lq = tid >> 4;
    float g1[4][4] = {}, g2[4][4] = {};
    for (int dc = 0; dc < 8; dc++) {
      const int d0 = dc * 32;
      __syncthreads();
      for (int idx = tid; idx < 2048; idx += 256) {
        const int r1 = idx >> 6, c1 = idx & 63;
        a1k[r1 * 64 + c1] = W1[(d0 + r1) * Hn + k0 + c1];
        a1l[r1 * 64 + c1] = W1[(d0 + r1) * Hn + l0 + c1];
      }
      for (int idx = tid; idx < 2048; idx += 256) {
        const int r1 = idx >> 5, c1 = idx & 31;
        w2kT[c1 * 72 + r1] = W2[(k0 + r1) * Dn + d0 + c1];
        w2lT[c1 * 72 + r1] = W2[(l0 + r1) * Dn + d0 + c1];
      }
      __syncthreads();
      #pragma unroll 4
      for (int dd = 0; dd < 32; dd++) {
        const float4 ak = *(const float4*)&a1k[dd * 64 + kq * 4];
        const float4 al = *(const float4*)&a1l[dd * 64 + lq * 4];
        const float4 wk = *(const float4*)&w2kT[dd * 72 + kq * 4];
        const float4 wl = *(const float4*)&w2lT[dd * 72 + lq * 4];
        const float akv[4] = {ak.x, ak.y, ak.z, ak.w};
        const float alv[4] = {al.x, al.y, al.z, al.w};
        const float wkv[4] = {wk.x, wk.y, wk.z, wk.w};
        const float wlv[4] = {wl.x, wl.y, wl.z, wl.w};
        #pragma unroll
        for (int i = 0; i < 4; i++)
          #pragma unroll
          for (int j = 0; j < 4; j++) {
            g1[i][j] += akv[i] * alv[j];
            g2[i][j] += wkv[i] * wlv[j];
          }
      }
    }
    #pragma unroll
    for (int i = 0; i < 4; i++)
      #pragma unroll
      for (int j = 0; j < 4; j++)
        Mm[(k0 + kq * 4 + i) * Hn + l0 + lq * 4 + j] = g1[i][j] * g2[i][j];
  } else if (wg < 512) {
    float* w2lT = sm;            // [64][72]
    float* w1t  = sm + 4608;     // [64][64]
    const int bw = wg - 256;
    const int e0 = (bw & 15) * 64, l0 = (bw >> 4) * 64;
    const int eq = tid & 15, lq = tid >> 4;
    float acc[4][4] = {};
    for (int dc = 0; dc < 4; dc++) {
      const int d0 = dc * 64;
      __syncthreads();
      for (int idx = tid; idx < 4096; idx += 256) {
        const int r1 = idx >> 6, c1 = idx & 63;
        w2lT[c1 * 72 + r1] = W2[(l0 + r1) * Dn + d0 + c1];
        w1t[r1 * 64 + c1] = W1[(d0 + r1) * Hn + e0 + c1];
      }
      __syncthreads();
      #pragma unroll 4
      for (int dd = 0; dd < 64; dd++) {
        const float4 wv = *(const float4*)&w2lT[dd * 72 + lq * 4];
        const float4 xv = *(const float4*)&w1t[dd * 64 + eq * 4];
        const float wvv[4] = {wv.x, wv.y, wv.z, wv.w};
        const float xvv[4] = {xv.x, xv.y, xv.z, xv.w};
        #pragma unroll
        for (int i = 0; i < 4; i++)
          #pragma unroll
          for (int j = 0; j < 4; j++)
            acc[i][j] += wvv[i] * xvv[j];
      }
    }
    #pragma unroll
    for (int i = 0; i < 4; i++)
      #pragma unroll
      for (int j = 0; j < 4; j++)
        Zz[(l0 + lq * 4 + i) * Hn + e0 + eq * 4 + j] = acc[i][j];
  } else if (wg == 512) {
    if (tid < 64) scal[tid] = 0.f;
    if (tid == 0) flags[0] = 0u;
  } else {
    // hbuf sentinel fill: 48 wgs x 8192 floats
    float* base = hbuf + (size_t)(wg - 513) * 8192;
    const f32x4 sent = {2.0f, 2.0f, 2.0f, 2.0f};
    for (int idx = tid; idx < 2048; idx += 256)
      *(f32x4*)&base[idx * 4] = sent;
  }
}

// ---------------- persistent main, data-as-flag ----------------
// wg 0..63: G (Z cols, publishes h)  wg 64..127: R (M)  wg 128..143: K (W2)
__global__ __launch_bounds__(512) void ode_main(
    const float* __restrict__ x0, const float* __restrict__ W1,
    const float* __restrict__ b1, const float* __restrict__ wt,
    const float* __restrict__ W2g, const float* __restrict__ b2,
    const float* __restrict__ mu, float* __restrict__ out,
    const float* __restrict__ Mm, const float* __restrict__ Zz,
    float* __restrict__ hbuf, float* __restrict__ scal,
    unsigned* __restrict__ flags) {
  __shared__ float Ms[16 * 1028];      // Mat slice [c][k]
  __shared__ float hsf[2][8 * 1028];   // h (or 1-h^2 for R), [ep][b][k]
  __shared__ float red[2][8][8][20];   // [ep][wv][cp][16]

  const int tid = threadIdx.x;
  const int wg = blockIdx.x;
  int role, cidx;
  if (wg < 64) { role = 0; cidx = wg; }
  else if (wg < 128) { role = 1; cidx = wg - 64; }
  else { role = 2; cidx = wg - 128; }
  const int wv = tid >> 6, lane = tid & 63;
  const int cp = lane & 7, ks = lane >> 3;
  const int b = tid >> 4, cl = tid & 15;    // epilogue mapping (tid<128)
  const int lh = lane >> 5, lc = lane & 31; // staging mapping

  float ubr = 0.f, xbr = 0.f;
  float b1c = 0.f, wtc = 0.f, bzc = 0.f, ccr = 0.f, b2c = 0.f, muc = 0.f;
  float gkr[6] = {}, kr[6] = {};
  float acc_a = 0.f, acc_b = 0.f;

  // ---- prologue (per-role constants computed directly) ----
  if (role == 0) {
    if (tid < 128) {
      const int col = 16 * cidx + cl;
      b1c = b1[col]; wtc = wt[col];
      float ub = 0.f, bzv = 0.f;
      for (int d = 0; d < Dn; ++d) {
        const float w1v = W1[d * Hn + col];
        ub  += x0[b * Dn + d] * w1v;
        bzv += b2[d] * w1v;
      }
      ubr = ub; bzc = bzv;
      const float h0 = fast_tanh(ubr + b1c);   // t = 0
      __hip_atomic_store(&hbuf[b * 1024 + col], h0, __ATOMIC_RELAXED,
                         __HIP_MEMORY_SCOPE_AGENT);  // fire & forget
    }
  } else if (role == 1) {
    if (tid < 128) {
      const int col = 16 * cidx + cl;
      float cv = 0.f;
      for (int d = 0; d < Dn; ++d)
        cv += W1[d * Hn + col] * W2g[col * Dn + d];
      ccr = cv;
    }
  } else {
    if (tid < 128) {
      const int d = 16 * cidx + cl;
      xbr = x0[b * Dn + d];
      muc = mu[d]; b2c = b2[d];
      float v = xbr * xbr;
      v += __shfl_xor(v, 1, 64); v += __shfl_xor(v, 2, 64);
      v += __shfl_xor(v, 4, 64); v += __shfl_xor(v, 8, 64);
      if (cl == 0) atomicAdd(&scal[b * 8 + 4], v);
    }
  }

  // ---- stage Mat slice into LDS ([c][k]) ----
  {
    const float* msrc = (role == 0) ? Zz : (role == 1) ? Mm : W2g;
    const int mld = (role == 2) ? Dn : Hn;
    const int cb = 16 * cidx;
    for (int j = 0; j < 32; ++j) {
      const int idx = j * 512 + tid;
      const int l = idx >> 4, c = idx & 15;
      Ms[c * 1028 + l] = msrc[l * mld + cb + c];
    }
  }
  __syncthreads();

  int ep = 0;
  // ---- main loop ----
  for (int n = 0; n < 8; ++n) {
    #pragma unroll
    for (int i = 0; i < 6; ++i) {
      const int s = n * 6 + i;
      if (role == 0 && s == 47) break;    // G: stage 47 feeds nothing
      if (role == 1 && i == 1) continue;  // R: BW[1]==0, output unused

      // ---- G: precompute u-partial (all terms except the pending gk_i) ----
      float upre = 0.f;
      if (role == 0 && tid < 128) {
        if (i == 5) {
          upre = ubr + DTf * (kBW[0] * gkr[0] + kBW[2] * gkr[2] +
                              kBW[3] * gkr[3] + kBW[4] * gkr[4]);
        } else {
          upre = ubr + b1c + wtc * (((float)n + kC[i + 1]) * DTf);
          #pragma unroll
          for (int j2 = 0; j2 < i; ++j2) upre += DTf * kA[i + 1][j2] * gkr[j2];
        }
      }

      // ---- poll + load own K-slice ----
      const float* hb0 = hbuf + (size_t)s * 8192 + (size_t)lh * 1024 +
                         128 * wv + 4 * lc;
      const float* q0 = hb0;
      const float* q1 = hb0 + 2048;
      const float* q2 = hb0 + 4096;
      const float* q3 = hb0 + 6144;
      f32x4 v0, v1, v2, v3;
      if (role == 0) {
        // G: fused probe+verify — one full sentinel-checked load per round
        int miss = 0;
        while (true) {
          asm volatile(
              "global_load_dwordx4 %0, %4, off sc0 sc1\n\t"
              "global_load_dwordx4 %1, %5, off sc0 sc1\n\t"
              "global_load_dwordx4 %2, %6, off sc0 sc1\n\t"
              "global_load_dwordx4 %3, %7, off sc0 sc1\n\t"
              "s_waitcnt vmcnt(0)"
              : "=&v"(v0), "=&v"(v1), "=&v"(v2), "=&v"(v3)
              : "v"(q0), "v"(q1), "v"(q2), "v"(q3)
              : "memory");
          const int bad =
              (v0.x == 2.0f) | (v0.y == 2.0f) | (v0.z == 2.0f) | (v0.w == 2.0f) |
              (v1.x == 2.0f) | (v1.y == 2.0f) | (v1.z == 2.0f) | (v1.w == 2.0f) |
              (v2.x == 2.0f) | (v2.y == 2.0f) | (v2.z == 2.0f) | (v2.w == 2.0f) |
              (v3.x == 2.0f) | (v3.y == 2.0f) | (v3.z == 2.0f) | (v3.w == 2.0f);
          if (!__any(bad)) break;
          if (miss >= 3)      __builtin_amdgcn_s_sleep(2);
          else if (miss == 2) __builtin_amdgcn_s_sleep(1);
          ++miss;  // miss 0,1: immediate retry
        }
      } else {
        // R/K: cheap probe then verify; lazy cadence (they trail the chain)
        while (true) {
          asm volatile(
              "global_load_dwordx4 %0, %1, off sc0 sc1\n\t"
              "s_waitcnt vmcnt(0)"
              : "=&v"(v3) : "v"(q3) : "memory");
          const int bad3 = (v3.x == 2.0f) | (v3.y == 2.0f) |
                           (v3.z == 2.0f) | (v3.w == 2.0f);
          if (!__any(bad3)) break;
          __builtin_amdgcn_s_sleep(16);
        }
        while (true) {
          asm volatile(
              "global_load_dwordx4 %0, %4, off sc0 sc1\n\t"
              "global_load_dwordx4 %1, %5, off sc0 sc1\n\t"
              "global_load_dwordx4 %2, %6, off sc0 sc1\n\t"
              "global_load_dwordx4 %3, %7, off sc0 sc1\n\t"
              "s_waitcnt vmcnt(0)"
              : "=&v"(v0), "=&v"(v1), "=&v"(v2), "=&v"(v3)
              : "v"(q0), "v"(q1), "v"(q2), "v"(q3)
              : "memory");
          const int bad =
              (v0.x == 2.0f) | (v0.y == 2.0f) | (v0.z == 2.0f) | (v0.w == 2.0f) |
              (v1.x == 2.0f) | (v1.y == 2.0f) | (v1.z == 2.0f) | (v1.w == 2.0f) |
              (v2.x == 2.0f) | (v2.y == 2.0f) | (v2.z == 2.0f) | (v2.w == 2.0f) |
              (v3.x == 2.0f) | (v3.y == 2.0f) | (v3.z == 2.0f) | (v3.w == 2.0f);
          if (!__any(bad)) break;
          __builtin_amdgcn_s_sleep(1);
        }
      }
      if (role == 1) {
        v0 = 1.0f - v0 * v0; v1 = 1.0f - v1 * v1;
        v2 = 1.0f - v2 * v2; v3 = 1.0f - v3 * v3;
      }
      {
        const int kofs = 128 * wv + 4 * lc;
        *(f32x4*)&hsf[ep][(0 + lh) * 1028 + kofs] = v0;
        *(f32x4*)&hsf[ep][(2 + lh) * 1028 + kofs] = v1;
        *(f32x4*)&hsf[ep][(4 + lh) * 1028 + kofs] = v2;
        *(f32x4*)&hsf[ep][(6 + lh) * 1028 + kofs] = v3;
      }

      // ---- matvec from LDS (wave-private K-slice) ----
      float av[16] = {};
      #pragma unroll
      for (int j = 0; j < 4; ++j) {
        const int kb = 128 * wv + 4 * ks + 32 * j;
        const f32x4 z0 = *(const f32x4*)&Ms[(2 * cp) * 1028 + kb];
        const f32x4 z1 = *(const f32x4*)&Ms[(2 * cp + 1) * 1028 + kb];
        #pragma unroll
        for (int bb = 0; bb < 8; ++bb) {
          const f32x4 hb = *(const f32x4*)&hsf[ep][bb * 1028 + kb];
          av[bb]     += z0.x * hb.x + z0.y * hb.y + z0.z * hb.z + z0.w * hb.w;
          av[8 + bb] += z1.x * hb.x + z1.y * hb.y + z1.z * hb.z + z1.w * hb.w;
        }
      }
      #pragma unroll
      for (int q = 0; q < 16; ++q) {
        av[q] += __shfl_xor(av[q], 8, 64);
        av[q] += __shfl_xor(av[q], 16, 64);
        av[q] += __shfl_xor(av[q], 32, 64);
      }
      if (ks == 0) {
        float* rp = &red[ep][wv][cp][0];
        #pragma unroll
        for (int q = 0; q < 16; ++q) rp[q] = av[q];
      }
      __syncthreads();   // red (and hsf for R's epilogue) complete

      // ---- epilogue (waves 0-1) ----
      if (tid < 128) {
        float r = 0.f;
        #pragma unroll
        for (int w = 0; w < 8; ++w)
          r += red[ep][w][cl >> 1][(cl & 1) * 8 + b];
        if (role == 0) {
          gkr[i] = r + bzc;
          float u;
          if (i == 5) {
            ubr = upre + DTf * kBW[5] * gkr[5];
            u = ubr + b1c + wtc * ((float)(n + 1) * DTf);
          } else {
            u = upre + DTf * kA[i + 1][i] * gkr[i];
          }
          const float hn2 = fast_tanh(u);
          __hip_atomic_store(
              &hbuf[(size_t)(s + 1) * 8192 + b * 1024 + 16 * cidx + cl], hn2,
              __ATOMIC_RELAXED, __HIP_MEMORY_SCOPE_AGENT);  // fire & forget
        } else if (role == 1) {
          const float sv = hsf[ep][b * 1028 + 16 * cidx + cl];
          float u1 = sv * r;        // -> jfn
          float u2 = sv * ccr;      // -> trJ
          u1 += __shfl_xor(u1, 1, 64); u2 += __shfl_xor(u2, 1, 64);
          u1 += __shfl_xor(u1, 2, 64); u2 += __shfl_xor(u2, 2, 64);
          u1 += __shfl_xor(u1, 4, 64); u2 += __shfl_xor(u2, 4, 64);
          u1 += __shfl_xor(u1, 8, 64); u2 += __shfl_xor(u2, 8, 64);
          if (cl == 0) {
            const float wgt = DTf * kBW[i];
            acc_a += -wgt * u2;   // dlogq = -trJ
            acc_b += wgt * u1;    // jfn
          }
        } else {
          const float kv = r + b2c;
          kr[i] = kv;
          float xi = xbr;
          #pragma unroll
          for (int j2 = 0; j2 < i; ++j2) xi += DTf * kA[i][j2] * kr[j2];
          float u1 = (xi - muc) * kv;   // -> kl
          float u2 = kv * kv;           // -> vfn
          u1 += __shfl_xor(u1, 1, 64); u2 += __shfl_xor(u2, 1, 64);
          u1 += __shfl_xor(u1, 2, 64); u2 += __shfl_xor(u2, 2, 64);
          u1 += __shfl_xor(u1, 4, 64); u2 += __shfl_xor(u2, 4, 64);
          u1 += __shfl_xor(u1, 8, 64); u2 += __shfl_xor(u2, 8, 64);
          if (cl == 0) {
            const float wgt = DTf * kBW[i];
            acc_a += wgt * u1;
            acc_b += wgt * u2;
          }
          if (i == 5)
            xbr += DTf * (kBW[0] * kr[0] + kBW[2] * kr[2] + kBW[3] * kr[3] +
                          kBW[4] * kr[4] + kBW[5] * kr[5]);
        }
      }
      ep ^= 1;
    }
  }

  // ---- finalize ----
  if (role == 1) {
    if (tid < 128 && cl == 0) {
      atomicAdd(&scal[b * 8 + 0], acc_a);
      atomicAdd(&scal[b * 8 + 3], acc_b);
    }
  } else if (role == 2) {
    if (tid < 128) out[b * 260 + 16 * cidx + cl] = xbr;
    if (tid < 128 && cl == 0) {
      atomicAdd(&scal[b * 8 + 1], acc_a);
      atomicAdd(&scal[b * 8 + 2], acc_b);
    }
  }
  if (role != 0) {
    asm volatile("s_waitcnt vmcnt(0)" ::: "memory");
    __syncthreads();
    if (tid == 0) {
      const unsigned old = __hip_atomic_fetch_add(&flags[0], 1u,
                                                  __ATOMIC_RELAXED,
                                                  __HIP_MEMORY_SCOPE_AGENT);
      if (old == 79u) {   // last of 80 consumers writes the scalar outputs
        for (int bb = 0; bb < Bn; ++bb) {
          const float trj = __hip_atomic_load(&scal[bb * 8 + 0], __ATOMIC_RELAXED, __HIP_MEMORY_SCOPE_AGENT);
          const float kl  = __hip_atomic_load(&scal[bb * 8 + 1], __ATOMIC_RELAXED, __HIP_MEMORY_SCOPE_AGENT);
          const float vfn = __hip_atomic_load(&scal[bb * 8 + 2], __ATOMIC_RELAXED, __HIP_MEMORY_SCOPE_AGENT);
          const float jfn = __hip_atomic_load(&scal[bb * 8 + 3], __ATOMIC_RELAXED, __HIP_MEMORY_SCOPE_AGENT);
          const float xsq = __hip_atomic_load(&scal[bb * 8 + 4], __ATOMIC_RELAXED, __HIP_MEMORY_SCOPE_AGENT);
          out[bb * 260 + 256] = -0.5f * (470.49652900079245f + xsq) + trj;
          out[bb * 260 + 257] = kl;
          out[bb * 260 + 258] = vfn;
          out[bb * 260 + 259] = jfn;
        }
      }
    }
  }
}

extern "C" void kernel_launch(void* const* d_in, const int* in_sizes, int n_in,
                              void* d_out, int out_size, void* d_ws, size_t ws_size,
                              hipStream_t stream) {
  (void)in_sizes; (void)n_in; (void)out_size; (void)ws_size;
  const float* x0 = (const float*)d_in[0];
  const float* W1 = (const float*)d_in[1];
  const float* b1 = (const float*)d_in[2];
  const float* wt = (const float*)d_in[3];
  const float* W2 = (const float*)d_in[4];
  const float* b2 = (const float*)d_in[5];
  const float* mu = (const float*)d_in[6];
  float* out = (float*)d_out;
  float* w = (float*)d_ws;

  float* Mm   = w;                  // 1048576
  float* Zz   = Mm + 1048576;       // 1048576
  float* hbuf = Zz + 1048576;       // 48*8192 = 393216 (64B-aligned)
  float* scal = hbuf + 393216;      // 64
  unsigned* flags = (unsigned*)(scal + 64);  // done counter

  precomp<<<dim3(561), dim3(256), 0, stream>>>(W1, W2, Mm, Zz, hbuf, scal, flags);
  ode_main<<<dim3(144), dim3(512), 0, stream>>>(x0, W1, b1, wt, W2, b2, mu, out,
                                                Mm, Zz, hbuf, scal, flags);
}

// Round 10
// 258.104 us; speedup vs baseline: 1.0568x; 1.0568x over previous
//
#include <hip/hip_runtime.h>
#include <math.h>

#define Hn 1024
#define Dn 256
#define Bn 8
#define DTf 0.125f

typedef __attribute__((ext_vector_type(4))) float f32x4;

constexpr float kA[6][5] = {
  {0.f, 0.f, 0.f, 0.f, 0.f},
  {1.0f/5.0f, 0.f, 0.f, 0.f, 0.f},
  {3.0f/40.0f, 9.0f/40.0f, 0.f, 0.f, 0.f},
  {44.0f/45.0f, -56.0f/15.0f, 32.0f/9.0f, 0.f, 0.f},
  {19372.0f/6561.0f, -25360.0f/2187.0f, 64448.0f/6561.0f, -212.0f/729.0f, 0.f},
  {9017.0f/3168.0f, -355.0f/33.0f, 46732.0f/5247.0f, 49.0f/176.0f, -5103.0f/18656.0f}
};
constexpr float kC[6] = {0.f, 0.2f, 0.3f, 0.8f, 8.0f/9.0f, 1.0f};
constexpr float kBW[6] = {35.0f/384.0f, 0.f, 500.0f/1113.0f, 125.0f/192.0f,
                          -2187.0f/6784.0f, 11.0f/84.0f};

__device__ __forceinline__ float fast_tanh(float x) {
  const float ax = fabsf(x);
  const float z = __expf(-2.0f * ax);
  const float t = (1.0f - z) * __builtin_amdgcn_rcpf(1.0f + z);
  return copysignf(t, x);
}

// ---------------- precompute ----------------
// wg 0..255: M = (W1^T W1).*(W2 W2^T); 256..511: Z = W2@W1;
// 512: scal/flags; 513..560: hbuf = 2.0f sentinel
__global__ __launch_bounds__(256) void precomp(
    const float* __restrict__ W1, const float* __restrict__ W2,
    float* __restrict__ Mm, float* __restrict__ Zz,
    float* __restrict__ hbuf, float* __restrict__ scal,
    unsigned* __restrict__ flags) {
  __shared__ float sm[8704];
  const int tid = threadIdx.x;
  const int wg = blockIdx.x;
  if (wg < 256) {
    float* a1k  = sm;            // [32][64]
    float* a1l  = sm + 2048;     // [32][64]
    float* w2kT = sm + 4096;     // [32][72]
    float* w2lT = sm + 6400;     // [32][72]
    const int k0 = (wg & 15) * 64, l0 = (wg >> 4) * 64;
    const int kq = tid & 15, lq = tid >> 4;
    float g1[4][4] = {}, g2[4][4] = {};
    for (int dc = 0; dc < 8; dc++) {
      const int d0 = dc * 32;
      __syncthreads();
      for (int idx = tid; idx < 2048; idx += 256) {
        const int r1 = idx >> 6, c1 = idx & 63;
        a1k[r1 * 64 + c1] = W1[(d0 + r1) * Hn + k0 + c1];
        a1l[r1 * 64 + c1] = W1[(d0 + r1) * Hn + l0 + c1];
      }
      for (int idx = tid; idx < 2048; idx += 256) {
        const int r1 = idx >> 5, c1 = idx & 31;
        w2kT[c1 * 72 + r1] = W2[(k0 + r1) * Dn + d0 + c1];
        w2lT[c1 * 72 + r1] = W2[(l0 + r1) * Dn + d0 + c1];
      }
      __syncthreads();
      #pragma unroll 4
      for (int dd = 0; dd < 32; dd++) {
        const float4 ak = *(const float4*)&a1k[dd * 64 + kq * 4];
        const float4 al = *(const float4*)&a1l[dd * 64 + lq * 4];
        const float4 wk = *(const float4*)&w2kT[dd * 72 + kq * 4];
        const float4 wl = *(const float4*)&w2lT[dd * 72 + lq * 4];
        const float akv[4] = {ak.x, ak.y, ak.z, ak.w};
        const float alv[4] = {al.x, al.y, al.z, al.w};
        const float wkv[4] = {wk.x, wk.y, wk.z, wk.w};
        const float wlv[4] = {wl.x, wl.y, wl.z, wl.w};
        #pragma unroll
        for (int i = 0; i < 4; i++)
          #pragma unroll
          for (int j = 0; j < 4; j++) {
            g1[i][j] += akv[i] * alv[j];
            g2[i][j] += wkv[i] * wlv[j];
          }
      }
    }
    #pragma unroll
    for (int i = 0; i < 4; i++)
      #pragma unroll
      for (int j = 0; j < 4; j++)
        Mm[(k0 + kq * 4 + i) * Hn + l0 + lq * 4 + j] = g1[i][j] * g2[i][j];
  } else if (wg < 512) {
    float* w2lT = sm;            // [64][72]
    float* w1t  = sm + 4608;     // [64][64]
    const int bw = wg - 256;
    const int e0 = (bw & 15) * 64, l0 = (bw >> 4) * 64;
    const int eq = tid & 15, lq = tid >> 4;
    float acc[4][4] = {};
    for (int dc = 0; dc < 4; dc++) {
      const int d0 = dc * 64;
      __syncthreads();
      for (int idx = tid; idx < 4096; idx += 256) {
        const int r1 = idx >> 6, c1 = idx & 63;
        w2lT[c1 * 72 + r1] = W2[(l0 + r1) * Dn + d0 + c1];
        w1t[r1 * 64 + c1] = W1[(d0 + r1) * Hn + e0 + c1];
      }
      __syncthreads();
      #pragma unroll 4
      for (int dd = 0; dd < 64; dd++) {
        const float4 wv = *(const float4*)&w2lT[dd * 72 + lq * 4];
        const float4 xv = *(const float4*)&w1t[dd * 64 + eq * 4];
        const float wvv[4] = {wv.x, wv.y, wv.z, wv.w};
        const float xvv[4] = {xv.x, xv.y, xv.z, xv.w};
        #pragma unroll
        for (int i = 0; i < 4; i++)
          #pragma unroll
          for (int j = 0; j < 4; j++)
            acc[i][j] += wvv[i] * xvv[j];
      }
    }
    #pragma unroll
    for (int i = 0; i < 4; i++)
      #pragma unroll
      for (int j = 0; j < 4; j++)
        Zz[(l0 + lq * 4 + i) * Hn + e0 + eq * 4 + j] = acc[i][j];
  } else if (wg == 512) {
    if (tid < 64) scal[tid] = 0.f;
    if (tid == 0) flags[0] = 0u;
  } else {
    // hbuf sentinel fill: 48 wgs x 8192 floats
    float* base = hbuf + (size_t)(wg - 513) * 8192;
    const f32x4 sent = {2.0f, 2.0f, 2.0f, 2.0f};
    for (int idx = tid; idx < 2048; idx += 256)
      *(f32x4*)&base[idx * 4] = sent;
  }
}

// ---------------- persistent main, data-as-flag ----------------
// wg 0..63: G (Z cols, publishes h)  wg 64..127: R (M)  wg 128..143: K (W2)
__global__ __launch_bounds__(512) void ode_main(
    const float* __restrict__ x0, const float* __restrict__ W1,
    const float* __restrict__ b1, const float* __restrict__ wt,
    const float* __restrict__ W2g, const float* __restrict__ b2,
    const float* __restrict__ mu, float* __restrict__ out,
    const float* __restrict__ Mm, const float* __restrict__ Zz,
    float* __restrict__ hbuf, float* __restrict__ scal,
    unsigned* __restrict__ flags) {
  __shared__ float Ms[16 * 1028];      // Mat slice [c][k]
  __shared__ float hsf[2][8 * 1028];   // h (or 1-h^2 for R), [ep][b][k]
  __shared__ float red[2][8][8][20];   // [ep][wv][cp][16]

  const int tid = threadIdx.x;
  const int wg = blockIdx.x;
  int role, cidx;
  if (wg < 64) { role = 0; cidx = wg; }
  else if (wg < 128) { role = 1; cidx = wg - 64; }
  else { role = 2; cidx = wg - 128; }
  const int wv = tid >> 6, lane = tid & 63;
  const int cp = lane & 7, ks = lane >> 3;
  const int b = tid >> 4, cl = tid & 15;    // epilogue mapping (tid<128)
  const int lh = lane >> 5, lc = lane & 31; // staging mapping

  float ubr = 0.f, xbr = 0.f;
  float b1c = 0.f, wtc = 0.f, bzc = 0.f, ccr = 0.f, b2c = 0.f, muc = 0.f;
  float gkr[6] = {}, kr[6] = {};
  float acc_a = 0.f, acc_b = 0.f;

  // ---- prologue (per-role constants computed directly) ----
  if (role == 0) {
    if (tid < 128) {
      const int col = 16 * cidx + cl;
      b1c = b1[col]; wtc = wt[col];
      float ub = 0.f, bzv = 0.f;
      for (int d = 0; d < Dn; ++d) {
        const float w1v = W1[d * Hn + col];
        ub  += x0[b * Dn + d] * w1v;
        bzv += b2[d] * w1v;
      }
      ubr = ub; bzc = bzv;
      const float h0 = fast_tanh(ubr + b1c);   // t = 0
      __hip_atomic_store(&hbuf[b * 1024 + col], h0, __ATOMIC_RELAXED,
                         __HIP_MEMORY_SCOPE_AGENT);  // fire & forget
    }
  } else if (role == 1) {
    if (tid < 128) {
      const int col = 16 * cidx + cl;
      float cv = 0.f;
      for (int d = 0; d < Dn; ++d)
        cv += W1[d * Hn + col] * W2g[col * Dn + d];
      ccr = cv;
    }
  } else {
    if (tid < 128) {
      const int d = 16 * cidx + cl;
      xbr = x0[b * Dn + d];
      muc = mu[d]; b2c = b2[d];
      float v = xbr * xbr;
      v += __shfl_xor(v, 1, 64); v += __shfl_xor(v, 2, 64);
      v += __shfl_xor(v, 4, 64); v += __shfl_xor(v, 8, 64);
      if (cl == 0) atomicAdd(&scal[b * 8 + 4], v);
    }
  }

  // ---- stage Mat slice into LDS ([c][k]) ----
  {
    const float* msrc = (role == 0) ? Zz : (role == 1) ? Mm : W2g;
    const int mld = (role == 2) ? Dn : Hn;
    const int cb = 16 * cidx;
    for (int j = 0; j < 32; ++j) {
      const int idx = j * 512 + tid;
      const int l = idx >> 4, c = idx & 15;
      Ms[c * 1028 + l] = msrc[l * mld + cb + c];
    }
  }
  __syncthreads();

  int ep = 0;
  // ---- main loop ----
  for (int n = 0; n < 8; ++n) {
    #pragma unroll
    for (int i = 0; i < 6; ++i) {
      const int s = n * 6 + i;
      if (role == 0 && s == 47) break;    // G: stage 47 feeds nothing
      if (role == 1 && i == 1) continue;  // R: BW[1]==0, output unused

      // ---- G: precompute u-partial (all terms except the pending gk_i) ----
      float upre = 0.f;
      if (role == 0 && tid < 128) {
        if (i == 5) {
          upre = ubr + DTf * (kBW[0] * gkr[0] + kBW[2] * gkr[2] +
                              kBW[3] * gkr[3] + kBW[4] * gkr[4]);
        } else {
          upre = ubr + b1c + wtc * (((float)n + kC[i + 1]) * DTf);
          #pragma unroll
          for (int j2 = 0; j2 < i; ++j2) upre += DTf * kA[i + 1][j2] * gkr[j2];
        }
      }

      // ---- probe (1KB/wave) with backoff, then full verified load ----
      const float* hb0 = hbuf + (size_t)s * 8192 + (size_t)lh * 1024 +
                         128 * wv + 4 * lc;
      const float* q0 = hb0;
      const float* q1 = hb0 + 2048;
      const float* q2 = hb0 + 4096;
      const float* q3 = hb0 + 6144;
      f32x4 v0, v1, v2, v3;
      {
        int miss = 0;
        while (true) {
          asm volatile(
              "global_load_dwordx4 %0, %1, off sc0 sc1\n\t"
              "s_waitcnt vmcnt(0)"
              : "=&v"(v3) : "v"(q3) : "memory");
          const int bad3 = (v3.x == 2.0f) | (v3.y == 2.0f) |
                           (v3.z == 2.0f) | (v3.w == 2.0f);
          if (!__any(bad3)) break;
          if (role == 0) {
            if (miss > 2)       __builtin_amdgcn_s_sleep(4);
            else if (miss == 2) __builtin_amdgcn_s_sleep(2);
            else if (miss == 1) __builtin_amdgcn_s_sleep(1);
            // miss==0: immediate retry
          } else {
            if (miss > 0) __builtin_amdgcn_s_sleep(32);
            else          __builtin_amdgcn_s_sleep(8);
          }
          ++miss;
        }
        while (true) {
          asm volatile(
              "global_load_dwordx4 %0, %4, off sc0 sc1\n\t"
              "global_load_dwordx4 %1, %5, off sc0 sc1\n\t"
              "global_load_dwordx4 %2, %6, off sc0 sc1\n\t"
              "global_load_dwordx4 %3, %7, off sc0 sc1\n\t"
              "s_waitcnt vmcnt(0)"
              : "=&v"(v0), "=&v"(v1), "=&v"(v2), "=&v"(v3)
              : "v"(q0), "v"(q1), "v"(q2), "v"(q3)
              : "memory");
          const int bad =
              (v0.x == 2.0f) | (v0.y == 2.0f) | (v0.z == 2.0f) | (v0.w == 2.0f) |
              (v1.x == 2.0f) | (v1.y == 2.0f) | (v1.z == 2.0f) | (v1.w == 2.0f) |
              (v2.x == 2.0f) | (v2.y == 2.0f) | (v2.z == 2.0f) | (v2.w == 2.0f) |
              (v3.x == 2.0f) | (v3.y == 2.0f) | (v3.z == 2.0f) | (v3.w == 2.0f);
          if (!__any(bad)) break;
          __builtin_amdgcn_s_sleep(1);
        }
      }
      if (role == 1) {
        v0 = 1.0f - v0 * v0; v1 = 1.0f - v1 * v1;
        v2 = 1.0f - v2 * v2; v3 = 1.0f - v3 * v3;
      }
      {
        const int kofs = 128 * wv + 4 * lc;
        *(f32x4*)&hsf[ep][(0 + lh) * 1028 + kofs] = v0;
        *(f32x4*)&hsf[ep][(2 + lh) * 1028 + kofs] = v1;
        *(f32x4*)&hsf[ep][(4 + lh) * 1028 + kofs] = v2;
        *(f32x4*)&hsf[ep][(6 + lh) * 1028 + kofs] = v3;
      }

      // ---- matvec from LDS (wave-private K-slice) ----
      float av[16] = {};
      #pragma unroll
      for (int j = 0; j < 4; ++j) {
        const int kb = 128 * wv + 4 * ks + 32 * j;
        const f32x4 z0 = *(const f32x4*)&Ms[(2 * cp) * 1028 + kb];
        const f32x4 z1 = *(const f32x4*)&Ms[(2 * cp + 1) * 1028 + kb];
        #pragma unroll
        for (int bb = 0; bb < 8; ++bb) {
          const f32x4 hb = *(const f32x4*)&hsf[ep][bb * 1028 + kb];
          av[bb]     += z0.x * hb.x + z0.y * hb.y + z0.z * hb.z + z0.w * hb.w;
          av[8 + bb] += z1.x * hb.x + z1.y * hb.y + z1.z * hb.z + z1.w * hb.w;
        }
      }
      #pragma unroll
      for (int q = 0; q < 16; ++q) {
        av[q] += __shfl_xor(av[q], 8, 64);
        av[q] += __shfl_xor(av[q], 16, 64);
        av[q] += __shfl_xor(av[q], 32, 64);
      }
      if (ks == 0) {
        float* rp = &red[ep][wv][cp][0];
        #pragma unroll
        for (int q = 0; q < 16; ++q) rp[q] = av[q];
      }
      __syncthreads();   // red (and hsf for R's epilogue) complete

      // ---- epilogue (waves 0-1) ----
      if (tid < 128) {
        float r = 0.f;
        #pragma unroll
        for (int w = 0; w < 8; ++w)
          r += red[ep][w][cl >> 1][(cl & 1) * 8 + b];
        if (role == 0) {
          gkr[i] = r + bzc;
          float u;
          if (i == 5) {
            ubr = upre + DTf * kBW[5] * gkr[5];
            u = ubr + b1c + wtc * ((float)(n + 1) * DTf);
          } else {
            u = upre + DTf * kA[i + 1][i] * gkr[i];
          }
          const float hn2 = fast_tanh(u);
          __hip_atomic_store(
              &hbuf[(size_t)(s + 1) * 8192 + b * 1024 + 16 * cidx + cl], hn2,
              __ATOMIC_RELAXED, __HIP_MEMORY_SCOPE_AGENT);  // fire & forget
        } else if (role == 1) {
          const float sv = hsf[ep][b * 1028 + 16 * cidx + cl];
          float u1 = sv * r;        // -> jfn
          float u2 = sv * ccr;      // -> trJ
          u1 += __shfl_xor(u1, 1, 64); u2 += __shfl_xor(u2, 1, 64);
          u1 += __shfl_xor(u1, 2, 64); u2 += __shfl_xor(u2, 2, 64);
          u1 += __shfl_xor(u1, 4, 64); u2 += __shfl_xor(u2, 4, 64);
          u1 += __shfl_xor(u1, 8, 64); u2 += __shfl_xor(u2, 8, 64);
          if (cl == 0) {
            const float wgt = DTf * kBW[i];
            acc_a += -wgt * u2;   // dlogq = -trJ
            acc_b += wgt * u1;    // jfn
          }
        } else {
          const float kv = r + b2c;
          kr[i] = kv;
          float xi = xbr;
          #pragma unroll
          for (int j2 = 0; j2 < i; ++j2) xi += DTf * kA[i][j2] * kr[j2];
          float u1 = (xi - muc) * kv;   // -> kl
          float u2 = kv * kv;           // -> vfn
          u1 += __shfl_xor(u1, 1, 64); u2 += __shfl_xor(u2, 1, 64);
          u1 += __shfl_xor(u1, 2, 64); u2 += __shfl_xor(u2, 2, 64);
          u1 += __shfl_xor(u1, 4, 64); u2 += __shfl_xor(u2, 4, 64);
          u1 += __shfl_xor(u1, 8, 64); u2 += __shfl_xor(u2, 8, 64);
          if (cl == 0) {
            const float wgt = DTf * kBW[i];
            acc_a += wgt * u1;
            acc_b += wgt * u2;
          }
          if (i == 5)
            xbr += DTf * (kBW[0] * kr[0] + kBW[2] * kr[2] + kBW[3] * kr[3] +
                          kBW[4] * kr[4] + kBW[5] * kr[5]);
        }
      }
      ep ^= 1;
    }
  }

  // ---- finalize ----
  if (role == 1) {
    if (tid < 128 && cl == 0) {
      atomicAdd(&scal[b * 8 + 0], acc_a);
      atomicAdd(&scal[b * 8 + 3], acc_b);
    }
  } else if (role == 2) {
    if (tid < 128) out[b * 260 + 16 * cidx + cl] = xbr;
    if (tid < 128 && cl == 0) {
      atomicAdd(&scal[b * 8 + 1], acc_a);
      atomicAdd(&scal[b * 8 + 2], acc_b);
    }
  }
  if (role != 0) {
    asm volatile("s_waitcnt vmcnt(0)" ::: "memory");
    __syncthreads();
    if (tid == 0) {
      const unsigned old = __hip_atomic_fetch_add(&flags[0], 1u,
                                                  __ATOMIC_RELAXED,
                                                  __HIP_MEMORY_SCOPE_AGENT);
      if (old == 79u) {   // last of 80 consumers writes the scalar outputs
        for (int bb = 0; bb < Bn; ++bb) {
          const float trj = __hip_atomic_load(&scal[bb * 8 + 0], __ATOMIC_RELAXED, __HIP_MEMORY_SCOPE_AGENT);
          const float kl  = __hip_atomic_load(&scal[bb * 8 + 1], __ATOMIC_RELAXED, __HIP_MEMORY_SCOPE_AGENT);
          const float vfn = __hip_atomic_load(&scal[bb * 8 + 2], __ATOMIC_RELAXED, __HIP_MEMORY_SCOPE_AGENT);
          const float jfn = __hip_atomic_load(&scal[bb * 8 + 3], __ATOMIC_RELAXED, __HIP_MEMORY_SCOPE_AGENT);
          const float xsq = __hip_atomic_load(&scal[bb * 8 + 4], __ATOMIC_RELAXED, __HIP_MEMORY_SCOPE_AGENT);
          out[bb * 260 + 256] = -0.5f * (470.49652900079245f + xsq) + trj;
          out[bb * 260 + 257] = kl;
          out[bb * 260 + 258] = vfn;
          out[bb * 260 + 259] = jfn;
        }
      }
    }
  }
}

extern "C" void kernel_launch(void* const* d_in, const int* in_sizes, int n_in,
                              void* d_out, int out_size, void* d_ws, size_t ws_size,
                              hipStream_t stream) {
  (void)in_sizes; (void)n_in; (void)out_size; (void)ws_size;
  const float* x0 = (const float*)d_in[0];
  const float* W1 = (const float*)d_in[1];
  const float* b1 = (const float*)d_in[2];
  const float* wt = (const float*)d_in[3];
  const float* W2 = (const float*)d_in[4];
  const float* b2 = (const float*)d_in[5];
  const float* mu = (const float*)d_in[6];
  float* out = (float*)d_out;
  float* w = (float*)d_ws;

  float* Mm   = w;                  // 1048576
  float* Zz   = Mm + 1048576;       // 1048576
  float* hbuf = Zz + 1048576;       // 48*8192 = 393216 (64B-aligned)
  float* scal = hbuf + 393216;      // 64
  unsigned* flags = (unsigned*)(scal + 64);  // done counter

  precomp<<<dim3(561), dim3(256), 0, stream>>>(W1, W2, Mm, Zz, hbuf, scal, flags);
  ode_main<<<dim3(144), dim3(512), 0, stream>>>(x0, W1, b1, wt, W2, b2, mu, out,
                                                Mm, Zz, hbuf, scal, flags);
}